// Round 9
// baseline (422.481 us; speedup 1.0000x reference)
//
#include <hip/hip_runtime.h>
#include <hip/hip_bf16.h>

#define NU 30000
#define NI 70000
#define NN 100000
#define DD 128
#define NLAYERS 3
#define SLOPE_ 0.01f
#define EPS_ 1e-12f

#define NB 782                 // row buckets of 128 rows
#define NBKT 1024              // padded bucket count (pow2)
#define NBLK 256               // scatter blocks
#define AROW 136               // LDS A row stride in ushorts (272B = 17*16B)
#define MAXL 32768             // max compacted rows for layer 3

typedef __bf16 v8bf __attribute__((ext_vector_type(8)));
typedef float v16f __attribute__((ext_vector_type(16)));
typedef unsigned short ushort_t;

union UB8 { uint4 u; v8bf v; };

__device__ __forceinline__ float bflo(unsigned u) { return __uint_as_float(u << 16); }
__device__ __forceinline__ float bfhi(unsigned u) { return __uint_as_float(u & 0xffff0000u); }

__device__ __forceinline__ unsigned pk2(float a, float b) {
    __hip_bfloat162 h = __float22bfloat162_rn(make_float2(a, b));
    return *reinterpret_cast<unsigned*>(&h);
}
__device__ __forceinline__ uint4 pk8(const float* f) {
    return make_uint4(pk2(f[0], f[1]), pk2(f[2], f[3]), pk2(f[4], f[5]), pk2(f[6], f[7]));
}
__device__ __forceinline__ void unp8(uint4 g, float* f) {
    f[0] = bflo(g.x); f[1] = bfhi(g.x);
    f[2] = bflo(g.y); f[3] = bfhi(g.y);
    f[4] = bflo(g.z); f[5] = bfhi(g.z);
    f[6] = bflo(g.w); f[7] = bfhi(g.w);
}
__device__ __forceinline__ ushort_t f2bf1(float x) {
    __hip_bfloat16 h = __float2bfloat16(x);
    return *reinterpret_cast<ushort_t*>(&h);
}

// ---------------------------------------------------------------- concat ----
__global__ __launch_bounds__(256) void k_concat_bf(const float* __restrict__ u,
                                                   const float* __restrict__ it,
                                                   ushort_t* __restrict__ fb) {
    int idx = blockIdx.x * 256 + threadIdx.x;
    if (idx >= NN * DD / 8) return;
    size_t base = (size_t)idx * 8;
    const float* src = (base < (size_t)NU * DD) ? (u + base) : (it + base - (size_t)NU * DD);
    float f[8];
    float4 a = *(const float4*)src;
    float4 b = *(const float4*)(src + 4);
    f[0] = a.x; f[1] = a.y; f[2] = a.z; f[3] = a.w;
    f[4] = b.x; f[5] = b.y; f[6] = b.z; f[7] = b.w;
    *(uint4*)(fb + base) = pk8(f);
}

// ---------------------------------------------------------------- zero ------
__global__ __launch_bounds__(256) void k_zero(float4* __restrict__ p, int n4) {
    int i = blockIdx.x * 256 + threadIdx.x;
    if (i < n4) p[i] = make_float4(0.f, 0.f, 0.f, 0.f);
}

// ---------------------------------------------------------------- dot -------
__global__ __launch_bounds__(256) void k_dot(const ushort_t* __restrict__ fb,
                                             const int* __restrict__ uIdx,
                                             const int* __restrict__ iIdx,
                                             float* __restrict__ out,
                                             int batch, int accum) {
    int b = blockIdx.x * 4 + (threadIdx.x >> 6);
    if (b >= batch) return;
    int lane = threadIdx.x & 63;
    unsigned ua = *(const unsigned*)(fb + (size_t)uIdx[b] * DD + lane * 2);
    unsigned ib = *(const unsigned*)(fb + (size_t)(iIdx[b] + NU) * DD + lane * 2);
    float s = bflo(ua) * bflo(ib) + bfhi(ua) * bfhi(ib);
#pragma unroll
    for (int m = 32; m; m >>= 1) s += __shfl_xor(s, m, 64);
    if (lane == 0) out[b] = accum ? out[b] + s : s;
}

// ------------------------------------------------- contention-free CSR build
__global__ __launch_bounds__(256) void k_lhist(const int* __restrict__ rows,
                                               int* __restrict__ ghist,
                                               int nnz, int epb) {
    __shared__ int h[NBKT];
    int t = threadIdx.x, b = blockIdx.x;
#pragma unroll
    for (int i = 0; i < 4; ++i) h[t + 256 * i] = 0;
    __syncthreads();
    int e0 = b * epb, e1 = min(e0 + epb, nnz);
    for (int e = e0 + t; e < e1; e += 256) atomicAdd(&h[rows[e] >> 7], 1);
    __syncthreads();
#pragma unroll
    for (int i = 0; i < 4; ++i) {
        int bkt = t + 256 * i;
        ghist[bkt * NBLK + b] = h[bkt];
    }
}

__global__ __launch_bounds__(256) void k_rscan(int* __restrict__ ghist,
                                               int* __restrict__ btot) {
    int t = threadIdx.x;
    int bkt = blockIdx.x * 4 + (t >> 6);
    int lane = t & 63;
    int* row = ghist + bkt * NBLK;
    int4 c = *(const int4*)(row + lane * 4);
    int s = c.x + c.y + c.z + c.w;
    int incl = s;
#pragma unroll
    for (int m = 1; m < 64; m <<= 1) {
        int o = __shfl_up(incl, m, 64);
        if (lane >= m) incl += o;
    }
    int excl = incl - s;
    int4 o;
    o.x = excl;
    o.y = o.x + c.x;
    o.z = o.y + c.y;
    o.w = o.z + c.z;
    *(int4*)(row + lane * 4) = o;
    if (lane == 63) btot[bkt] = incl;
}

__global__ __launch_bounds__(256) void k_btscan(const int* __restrict__ btot,
                                                int* __restrict__ bbase) {
    int t = threadIdx.x;
    int4 c = *(const int4*)(btot + t * 4);
    int tsum = c.x + c.y + c.z + c.w;
    int incl = tsum;
#pragma unroll
    for (int m = 1; m < 64; m <<= 1) {
        int o = __shfl_up(incl, m, 64);
        if ((t & 63) >= m) incl += o;
    }
    __shared__ int wsum[4];
    if ((t & 63) == 63) wsum[t >> 6] = incl;
    __syncthreads();
    int off = 0;
    for (int i = 0; i < (t >> 6); ++i) off += wsum[i];
    int excl = off + incl - tsum;
    int4 o;
    o.x = excl;
    o.y = o.x + c.x;
    o.z = o.y + c.y;
    o.w = o.z + c.z;
    *(int4*)(bbase + t * 4) = o;
    if (t == 255) bbase[NBKT] = o.w + c.w;
}

__global__ __launch_bounds__(256) void k_sscatter(const int* __restrict__ rows,
                                                  const int* __restrict__ cols,
                                                  const float* __restrict__ vals,
                                                  const int* __restrict__ ghist,
                                                  const int* __restrict__ bbase,
                                                  int2* __restrict__ bedges,
                                                  int nnz, int epb) {
    __shared__ int base[NBKT];
    __shared__ int h[NBKT];
    int t = threadIdx.x, b = blockIdx.x;
#pragma unroll
    for (int i = 0; i < 4; ++i) {
        int bkt = t + 256 * i;
        base[bkt] = bbase[bkt] + ghist[bkt * NBLK + b];
        h[bkt] = 0;
    }
    __syncthreads();
    int e0 = b * epb, e1 = min(e0 + epb, nnz);
    for (int e = e0 + t; e < e1; e += 256) {
        int r = rows[e];
        int bkt = r >> 7;
        int rank = atomicAdd(&h[bkt], 1);
        bedges[base[bkt] + rank] = make_int2(((r & 127) << 20) | cols[e],
                                             __float_as_int(vals[e]));
    }
}

__global__ __launch_bounds__(256) void k_csort(const int* __restrict__ bbase,
                                               const int2* __restrict__ bedges,
                                               int2* __restrict__ edges,
                                               int* __restrict__ rowPtr, int nnz) {
    __shared__ int cntS[128];
    __shared__ int fillS[128];
    __shared__ int wtot;
    int b = blockIdx.x, t = threadIdx.x;
    int s0 = bbase[b];
    int s1 = bbase[b + 1];
    if (t < 128) cntS[t] = 0;
    __syncthreads();
    for (int i = s0 + t; i < s1; i += 256) atomicAdd(&cntS[bedges[i].x >> 20], 1);
    __syncthreads();
    int v = 0, incl = 0;
    if (t < 128) {
        v = cntS[t];
        incl = v;
#pragma unroll
        for (int m = 1; m < 64; m <<= 1) {
            int o = __shfl_up(incl, m, 64);
            if ((t & 63) >= m) incl += o;
        }
        if (t == 63) wtot = incl;
    }
    __syncthreads();
    if (t < 128) {
        int excl = incl - v + ((t >= 64) ? wtot : 0);
        fillS[t] = excl;
        int gr = b * 128 + t;
        if (gr < NN) rowPtr[gr] = s0 + excl;
    }
    if (b == 0 && t == 0) rowPtr[NN] = nnz;
    __syncthreads();
    for (int i = s0 + t; i < s1; i += 256) {
        int2 e = bedges[i];
        int r = e.x >> 20;
        int p = atomicAdd(&fillS[r], 1);
        edges[s0 + p] = make_int2(e.x & 0xFFFFF, e.y);
    }
}

// --------------------------------------------- layer-3 row list (flags) -----
__global__ __launch_bounds__(256) void k_flag(const int* __restrict__ uIdx,
                                              const int* __restrict__ iIdx,
                                              int* __restrict__ flags,
                                              int* __restrict__ cnt, int batch) {
    int i = blockIdx.x * 256 + threadIdx.x;
    if (i == 0) *cnt = 0;
    if (i < batch) flags[uIdx[i]] = 1;
    else if (i < 2 * batch) flags[iIdx[i - batch] + NU] = 1;
}

__global__ __launch_bounds__(256) void k_compact(const int* __restrict__ flags,
                                                 int* __restrict__ list,
                                                 int* __restrict__ cnt) {
    int i = blockIdx.x * 256 + threadIdx.x;
    int f = (i < NN) ? flags[i] : 0;
    unsigned long long mask = __ballot(f);
    int lane = threadIdx.x & 63;
    int total = __popcll(mask);
    int prefix = __popcll(mask & ((1ULL << lane) - 1));
    int base = 0;
    if (lane == 0 && total) base = atomicAdd(cnt, total);
    base = __shfl(base, 0, 64);
    if (f) list[base + prefix] = i;
}

// ---------------------------------------------------------------- wprep -----
__global__ __launch_bounds__(256) void k_wprep(const float* __restrict__ Wlin,
                                               const float* __restrict__ Wint,
                                               uint4* __restrict__ Wb4) {
    int id = blockIdx.x * 256 + threadIdx.x;   // 0..12287
    int lane = id & 63;
    int w = (id >> 6) & 3;
    int s = (id >> 8) & 7;
    int c = (id >> 11) & 1;
    int l = id >> 12;
    const float* src = (c ? Wint : Wlin) + (size_t)l * DD * DD;
    int n = w * 32 + (lane & 31);
    int k0 = s * 16 + ((lane >> 5) & 1) * 8;
    float f[8];
#pragma unroll
    for (int j = 0; j < 8; ++j) f[j] = src[(size_t)(k0 + j) * DD + n];
    Wb4[id] = pk8(f);
}

// ---------------------------------------------------------------- spmm ------
// one wave per row; quarter-wave per edge; 4 edges in flight per quarter.
__device__ __forceinline__ void spmm_row(int r, int l,
                                         const int* __restrict__ rowPtr,
                                         const int2* __restrict__ edges,
                                         const ushort_t* __restrict__ fb,
                                         ushort_t* __restrict__ Lxb) {
    int q = l >> 4;
    int d0 = (l & 15) * 8;
    int beg = rowPtr[r], end = rowPtr[r + 1];
    float acc[8] = {0.f, 0.f, 0.f, 0.f, 0.f, 0.f, 0.f, 0.f};
    int e = beg + q;
    for (; e + 12 < end; e += 16) {
        int2 p0 = edges[e];
        int2 p1 = edges[e + 4];
        int2 p2 = edges[e + 8];
        int2 p3 = edges[e + 12];
        uint4 g0 = *(const uint4*)(fb + (size_t)p0.x * DD + d0);
        uint4 g1 = *(const uint4*)(fb + (size_t)p1.x * DD + d0);
        uint4 g2 = *(const uint4*)(fb + (size_t)p2.x * DD + d0);
        uint4 g3 = *(const uint4*)(fb + (size_t)p3.x * DD + d0);
        float v0 = __int_as_float(p0.y), v1 = __int_as_float(p1.y);
        float v2 = __int_as_float(p2.y), v3 = __int_as_float(p3.y);
        float x[8];
        unp8(g0, x);
#pragma unroll
        for (int j = 0; j < 8; ++j) acc[j] = fmaf(v0, x[j], acc[j]);
        unp8(g1, x);
#pragma unroll
        for (int j = 0; j < 8; ++j) acc[j] = fmaf(v1, x[j], acc[j]);
        unp8(g2, x);
#pragma unroll
        for (int j = 0; j < 8; ++j) acc[j] = fmaf(v2, x[j], acc[j]);
        unp8(g3, x);
#pragma unroll
        for (int j = 0; j < 8; ++j) acc[j] = fmaf(v3, x[j], acc[j]);
    }
    for (; e < end; e += 4) {
        int2 p0 = edges[e];
        uint4 g0 = *(const uint4*)(fb + (size_t)p0.x * DD + d0);
        float v0 = __int_as_float(p0.y);
        float x[8];
        unp8(g0, x);
#pragma unroll
        for (int j = 0; j < 8; ++j) acc[j] = fmaf(v0, x[j], acc[j]);
    }
#pragma unroll
    for (int j = 0; j < 8; ++j) {
        acc[j] += __shfl_xor(acc[j], 16, 64);
        acc[j] += __shfl_xor(acc[j], 32, 64);
    }
    if (l < 16) *(uint4*)(Lxb + (size_t)r * DD + d0) = pk8(acc);
}

__global__ __launch_bounds__(256) void k_spmm_bf(const int* __restrict__ rowPtr,
                                                 const int2* __restrict__ edges,
                                                 const ushort_t* __restrict__ fb,
                                                 ushort_t* __restrict__ Lxb) {
    int r = blockIdx.x * 4 + (threadIdx.x >> 6);
    if (r >= NN) return;
    spmm_row(r, threadIdx.x & 63, rowPtr, edges, fb, Lxb);
}

__global__ __launch_bounds__(256) void k_spmm_idx(const int* __restrict__ rowPtr,
                                                  const int2* __restrict__ edges,
                                                  const ushort_t* __restrict__ fb,
                                                  ushort_t* __restrict__ Lxb,
                                                  const int* __restrict__ list,
                                                  const int* __restrict__ cnt) {
    int i = blockIdx.x * 4 + (threadIdx.x >> 6);
    if (i >= *cnt) return;
    spmm_row(list[i], threadIdx.x & 63, rowPtr, edges, fb, Lxb);
}

// ---------------------------------------------------------------- layer -----
template <bool INDEXED>
__device__ __forceinline__ void layer_body(const ushort_t* __restrict__ Lxb,
                                           const uint4* __restrict__ Wb4,
                                           const float* __restrict__ blin,
                                           const float* __restrict__ bint,
                                           ushort_t* __restrict__ fb,
                                           const ushort_t* __restrict__ fin,
                                           const int* __restrict__ list, int nc) {
    __shared__ ushort_t As[128 * AROW];    // 34816 B
    __shared__ float pnormAll[128 * 4];    // 2048 B
    __shared__ float rinvS[128];           // 512 B
    __shared__ int rowIdS[128];            // 512 B

    const int t = threadIdx.x;
    const int w = t >> 6;
    const int l = t & 63;
    const int q = l >> 5;
    const int ln = l & 31;
    const int n = w * 32 + ln;
    const int m0 = blockIdx.x * 128;

    if (t < 128) {
        int gi = m0 + t;
        int gm;
        if (INDEXED) gm = (gi < nc) ? list[gi] : -1;
        else gm = (gi < NN) ? gi : -1;
        rowIdS[t] = gm;
    }
    __syncthreads();

    const float bias = blin[n] + bint[n];

    v16f acc[4];
#pragma unroll
    for (int mt = 0; mt < 4; ++mt)
#pragma unroll
        for (int i = 0; i < 16; ++i) acc[mt][i] = 0.f;

    for (int c = 0; c < 2; ++c) {
#pragma unroll
        for (int ii = 0; ii < 8; ++ii) {
            int idx = ii * 256 + t;
            int row = idx >> 4;
            int ch = idx & 15;
            int gm = rowIdS[row];
            uint4 outv = make_uint4(0, 0, 0, 0);
            if (gm >= 0) {
                uint4 gl = *(const uint4*)(Lxb + (size_t)gm * DD + ch * 8);
                uint4 gf = *(const uint4*)(fin + (size_t)gm * DD + ch * 8);
                float a[8], b[8], r[8];
                unp8(gl, a);
                unp8(gf, b);
                if (c == 0) {
#pragma unroll
                    for (int j = 0; j < 8; ++j) r[j] = a[j] + b[j];
                } else {
#pragma unroll
                    for (int j = 0; j < 8; ++j) r[j] = a[j] * b[j];
                }
                outv = pk8(r);
            }
            *(uint4*)&As[row * AROW + ch * 8] = outv;
        }
        __syncthreads();

        UB8 bf[8];
#pragma unroll
        for (int s = 0; s < 8; ++s) bf[s].u = Wb4[c * 2048 + s * 256 + w * 64 + l];

#pragma unroll
        for (int mt = 0; mt < 4; ++mt) {
#pragma unroll
            for (int s = 0; s < 8; ++s) {
                v8bf af = *(const v8bf*)&As[(mt * 32 + ln) * AROW + s * 16 + q * 8];
                acc[mt] = __builtin_amdgcn_mfma_f32_32x32x16_bf16(af, bf[s].v, acc[mt], 0, 0, 0);
            }
        }
        __syncthreads();
    }

#pragma unroll
    for (int mt = 0; mt < 4; ++mt) {
        float r[16];
#pragma unroll
        for (int reg = 0; reg < 16; ++reg) {
            float v = acc[mt][reg] + bias;
            v = (v > 0.f) ? v : SLOPE_ * v;
            acc[mt][reg] = v;
            r[reg] = v * v;
        }
#pragma unroll
        for (int lev = 0; lev < 4; ++lev) {
            int m = 1 << lev;
            int cnt2 = 8 >> lev;
            bool hi = (l & m) != 0;
#pragma unroll
            for (int i = 0; i < 8; ++i) {
                if (i < cnt2) {
                    float p = hi ? r[2 * i + 1] : r[2 * i];
                    float qv = hi ? r[2 * i] : r[2 * i + 1];
                    r[i] = p + __shfl_xor(qv, m, 64);
                }
            }
        }
        float tot = r[0] + __shfl_xor(r[0], 16, 64);
        if ((l & 31) < 16) {
            int i = l & 15;
            int row = (i & 3) + ((i >> 2) << 3) + 4 * q;
            pnormAll[(mt * 32 + row) * 4 + w] = tot;
        }
    }
    __syncthreads();
    if (t < 128) {
        float4 p = *(const float4*)&pnormAll[t * 4];
        float tot = p.x + p.y + p.z + p.w;
        rinvS[t] = 1.0f / fmaxf(sqrtf(tot), EPS_);
    }
    __syncthreads();

#pragma unroll
    for (int mt = 0; mt < 4; ++mt) {
#pragma unroll
        for (int reg = 0; reg < 16; ++reg) {
            int row = (reg & 3) + ((reg >> 2) << 3) + 4 * q;
            int gm = rowIdS[mt * 32 + row];
            if (gm >= 0)
                fb[(size_t)gm * DD + n] = f2bf1(acc[mt][reg] * rinvS[mt * 32 + row]);
        }
    }
}

// block=256, min 3 waves/EU: VGPR cap ~170 — kernel needs ~84+64acc, (256,4)
// forced 128-cap and spilled (+6MB WRITE, R8). Keep at 3.
__global__ __launch_bounds__(256, 3) void k_layer2(const ushort_t* __restrict__ Lxb,
                                                   const uint4* __restrict__ Wb4,
                                                   const float* __restrict__ blin,
                                                   const float* __restrict__ bint,
                                                   const ushort_t* __restrict__ fin,
                                                   ushort_t* __restrict__ fb) {
    layer_body<false>(Lxb, Wb4, blin, bint, fb, fin, nullptr, 0);
}

__global__ __launch_bounds__(256, 3) void k_layer_idx(const ushort_t* __restrict__ Lxb,
                                                      const uint4* __restrict__ Wb4,
                                                      const float* __restrict__ blin,
                                                      const float* __restrict__ bint,
                                                      const ushort_t* __restrict__ fin,
                                                      ushort_t* __restrict__ fb,
                                                      const int* __restrict__ list,
                                                      const int* __restrict__ cnt) {
    layer_body<true>(Lxb, Wb4, blin, bint, fb, fin, list, *cnt);
}

// ---------------------------------------------------------------- launch ----
extern "C" void kernel_launch(void* const* d_in, const int* in_sizes, int n_in,
                              void* d_out, int out_size, void* d_ws, size_t ws_size,
                              hipStream_t stream) {
    const int*   userIdx = (const int*)d_in[0];
    const int*   itemIdx = (const int*)d_in[1];
    const int*   rows    = (const int*)d_in[2];
    const int*   cols    = (const int*)d_in[3];
    const float* vals    = (const float*)d_in[4];
    const float* uE      = (const float*)d_in[5];
    const float* iE      = (const float*)d_in[6];
    const float* Wlin    = (const float*)d_in[7];
    const float* blin    = (const float*)d_in[8];
    const float* Wint    = (const float*)d_in[9];
    const float* bint    = (const float*)d_in[10];
    float* out = (float*)d_out;

    const int batch = in_sizes[0];
    const int nnz   = in_sizes[2];
    const int epb   = (nnz + NBLK - 1) / NBLK;

    // ---- workspace layout ----
    ushort_t* featA = (ushort_t*)d_ws;                       // 25.6 MB
    ushort_t* featB = featA + (size_t)NN * DD;               // 25.6 MB (ping-pong)
    ushort_t* Lxb   = featB + (size_t)NN * DD;               // 25.6 MB
    uint4* Wb4      = (uint4*)(Lxb + (size_t)NN * DD);       // 196 KB
    int2*  bedges   = (int2*)(Wb4 + 12288);                  // 8 MB
    int2*  edges    = bedges + nnz;                          // 8 MB
    int*   ghist    = (int*)(edges + nnz);                   // 1 MB
    int*   btot     = ghist + NBKT * NBLK;                   // 4 KB
    int*   bbase    = btot + NBKT;                           // 4 KB (+1)
    int*   rowPtr   = bbase + NBKT + 4;                      // NN+1
    int*   flags    = rowPtr + NN + 4;                       // 400 KB
    int*   list     = flags + NN;                            // 128 KB
    int*   cnt      = list + MAXL;                           // 4 B

    k_concat_bf<<<(NN * DD / 8 + 255) / 256, 256, 0, stream>>>(uE, iE, featA);
    k_wprep<<<48, 256, 0, stream>>>(Wlin, Wint, Wb4);

    // ---- contention-free CSR build (hierarchical scan) ----
    k_lhist<<<NBLK, 256, 0, stream>>>(rows, ghist, nnz, epb);
    k_rscan<<<NBKT / 4, 256, 0, stream>>>(ghist, btot);
    k_btscan<<<1, 256, 0, stream>>>(btot, bbase);
    k_sscatter<<<NBLK, 256, 0, stream>>>(rows, cols, vals, ghist, bbase, bedges, nnz, epb);
    k_csort<<<NB, 256, 0, stream>>>(bbase, bedges, edges, rowPtr, nnz);

    // ---- layer-3 row list ----
    k_zero<<<(NN / 4 + 255) / 256, 256, 0, stream>>>((float4*)flags, NN / 4);
    k_flag<<<(2 * batch + 255) / 256, 256, 0, stream>>>(userIdx, itemIdx, flags, cnt, batch);
    k_compact<<<(NN + 255) / 256, 256, 0, stream>>>(flags, list, cnt);

    k_dot<<<(batch + 3) / 4, 256, 0, stream>>>(featA, userIdx, itemIdx, out, batch, 0);

    // layer 1: featA -> featB
    k_spmm_bf<<<(NN + 3) / 4, 256, 0, stream>>>(rowPtr, edges, featA, Lxb);
    k_layer2<<<(NN + 127) / 128, 256, 0, stream>>>(
        Lxb, Wb4, blin, bint, featA, featB);
    k_dot<<<(batch + 3) / 4, 256, 0, stream>>>(featB, userIdx, itemIdx, out, batch, 1);

    // layer 2: featB -> featA
    k_spmm_bf<<<(NN + 3) / 4, 256, 0, stream>>>(rowPtr, edges, featB, Lxb);
    k_layer2<<<(NN + 127) / 128, 256, 0, stream>>>(
        Lxb, Wb4 + 4096, blin + DD, bint + DD, featB, featA);
    k_dot<<<(batch + 3) / 4, 256, 0, stream>>>(featA, userIdx, itemIdx, out, batch, 1);

    // layer 3 (sparse rows): featA -> featB, only listed rows
    k_spmm_idx<<<(MAXL + 3) / 4, 256, 0, stream>>>(rowPtr, edges, featA, Lxb, list, cnt);
    k_layer_idx<<<(MAXL + 127) / 128, 256, 0, stream>>>(
        Lxb, Wb4 + 8192, blin + 2 * DD, bint + 2 * DD, featA, featB, list, cnt);
    k_dot<<<(batch + 3) / 4, 256, 0, stream>>>(featB, userIdx, itemIdx, out, batch, 1);
}

// Round 10
// 378.836 us; speedup vs baseline: 1.1152x; 1.1152x over previous
//
#include <hip/hip_runtime.h>
#include <hip/hip_bf16.h>

#define NU 30000
#define NI 70000
#define NN 100000
#define DD 128
#define NLAYERS 3
#define SLOPE_ 0.01f
#define EPS_ 1e-12f

#define NB 782                 // row buckets of 128 rows
#define NBKT 1024              // padded bucket count (pow2)
#define NBLK 256               // scatter blocks
#define AROW 136               // LDS A row stride in ushorts (272B = 17*16B)
#define MAXL 32768             // max compacted rows for layer 3
#define BM 64                  // layer kernel M-tile (64 rows/block)

typedef __bf16 v8bf __attribute__((ext_vector_type(8)));
typedef float v16f __attribute__((ext_vector_type(16)));
typedef unsigned short ushort_t;

union UB8 { uint4 u; v8bf v; };

__device__ __forceinline__ float bflo(unsigned u) { return __uint_as_float(u << 16); }
__device__ __forceinline__ float bfhi(unsigned u) { return __uint_as_float(u & 0xffff0000u); }

__device__ __forceinline__ unsigned pk2(float a, float b) {
    __hip_bfloat162 h = __float22bfloat162_rn(make_float2(a, b));
    return *reinterpret_cast<unsigned*>(&h);
}
__device__ __forceinline__ uint4 pk8(const float* f) {
    return make_uint4(pk2(f[0], f[1]), pk2(f[2], f[3]), pk2(f[4], f[5]), pk2(f[6], f[7]));
}
__device__ __forceinline__ void unp8(uint4 g, float* f) {
    f[0] = bflo(g.x); f[1] = bfhi(g.x);
    f[2] = bflo(g.y); f[3] = bfhi(g.y);
    f[4] = bflo(g.z); f[5] = bfhi(g.z);
    f[6] = bflo(g.w); f[7] = bfhi(g.w);
}
__device__ __forceinline__ ushort_t f2bf1(float x) {
    __hip_bfloat16 h = __float2bfloat16(x);
    return *reinterpret_cast<ushort_t*>(&h);
}

// ---------------------------------------------------------------- concat ----
__global__ __launch_bounds__(256) void k_concat_bf(const float* __restrict__ u,
                                                   const float* __restrict__ it,
                                                   ushort_t* __restrict__ fb) {
    int idx = blockIdx.x * 256 + threadIdx.x;
    if (idx >= NN * DD / 8) return;
    size_t base = (size_t)idx * 8;
    const float* src = (base < (size_t)NU * DD) ? (u + base) : (it + base - (size_t)NU * DD);
    float f[8];
    float4 a = *(const float4*)src;
    float4 b = *(const float4*)(src + 4);
    f[0] = a.x; f[1] = a.y; f[2] = a.z; f[3] = a.w;
    f[4] = b.x; f[5] = b.y; f[6] = b.z; f[7] = b.w;
    *(uint4*)(fb + base) = pk8(f);
}

// ---------------------------------------------------------------- zero ------
__global__ __launch_bounds__(256) void k_zero(float4* __restrict__ p, int n4) {
    int i = blockIdx.x * 256 + threadIdx.x;
    if (i < n4) p[i] = make_float4(0.f, 0.f, 0.f, 0.f);
}

// ---------------------------------------------------------------- dot -------
__global__ __launch_bounds__(256) void k_dot(const ushort_t* __restrict__ fb,
                                             const int* __restrict__ uIdx,
                                             const int* __restrict__ iIdx,
                                             float* __restrict__ out,
                                             int batch, int accum) {
    int b = blockIdx.x * 4 + (threadIdx.x >> 6);
    if (b >= batch) return;
    int lane = threadIdx.x & 63;
    unsigned ua = *(const unsigned*)(fb + (size_t)uIdx[b] * DD + lane * 2);
    unsigned ib = *(const unsigned*)(fb + (size_t)(iIdx[b] + NU) * DD + lane * 2);
    float s = bflo(ua) * bflo(ib) + bfhi(ua) * bfhi(ib);
#pragma unroll
    for (int m = 32; m; m >>= 1) s += __shfl_xor(s, m, 64);
    if (lane == 0) out[b] = accum ? out[b] + s : s;
}

// ------------------------------------------------- contention-free CSR build
__global__ __launch_bounds__(256) void k_lhist(const int* __restrict__ rows,
                                               int* __restrict__ ghist,
                                               int nnz, int epb) {
    __shared__ int h[NBKT];
    int t = threadIdx.x, b = blockIdx.x;
#pragma unroll
    for (int i = 0; i < 4; ++i) h[t + 256 * i] = 0;
    __syncthreads();
    int e0 = b * epb, e1 = min(e0 + epb, nnz);
    for (int e = e0 + t; e < e1; e += 256) atomicAdd(&h[rows[e] >> 7], 1);
    __syncthreads();
#pragma unroll
    for (int i = 0; i < 4; ++i) {
        int bkt = t + 256 * i;
        ghist[bkt * NBLK + b] = h[bkt];
    }
}

__global__ __launch_bounds__(256) void k_rscan(int* __restrict__ ghist,
                                               int* __restrict__ btot) {
    int t = threadIdx.x;
    int bkt = blockIdx.x * 4 + (t >> 6);
    int lane = t & 63;
    int* row = ghist + bkt * NBLK;
    int4 c = *(const int4*)(row + lane * 4);
    int s = c.x + c.y + c.z + c.w;
    int incl = s;
#pragma unroll
    for (int m = 1; m < 64; m <<= 1) {
        int o = __shfl_up(incl, m, 64);
        if (lane >= m) incl += o;
    }
    int excl = incl - s;
    int4 o;
    o.x = excl;
    o.y = o.x + c.x;
    o.z = o.y + c.y;
    o.w = o.z + c.z;
    *(int4*)(row + lane * 4) = o;
    if (lane == 63) btot[bkt] = incl;
}

__global__ __launch_bounds__(256) void k_btscan(const int* __restrict__ btot,
                                                int* __restrict__ bbase) {
    int t = threadIdx.x;
    int4 c = *(const int4*)(btot + t * 4);
    int tsum = c.x + c.y + c.z + c.w;
    int incl = tsum;
#pragma unroll
    for (int m = 1; m < 64; m <<= 1) {
        int o = __shfl_up(incl, m, 64);
        if ((t & 63) >= m) incl += o;
    }
    __shared__ int wsum[4];
    if ((t & 63) == 63) wsum[t >> 6] = incl;
    __syncthreads();
    int off = 0;
    for (int i = 0; i < (t >> 6); ++i) off += wsum[i];
    int excl = off + incl - tsum;
    int4 o;
    o.x = excl;
    o.y = o.x + c.x;
    o.z = o.y + c.y;
    o.w = o.z + c.z;
    *(int4*)(bbase + t * 4) = o;
    if (t == 255) bbase[NBKT] = o.w + c.w;
}

__global__ __launch_bounds__(256) void k_sscatter(const int* __restrict__ rows,
                                                  const int* __restrict__ cols,
                                                  const float* __restrict__ vals,
                                                  const int* __restrict__ ghist,
                                                  const int* __restrict__ bbase,
                                                  int2* __restrict__ bedges,
                                                  int nnz, int epb) {
    __shared__ int base[NBKT];
    __shared__ int h[NBKT];
    int t = threadIdx.x, b = blockIdx.x;
#pragma unroll
    for (int i = 0; i < 4; ++i) {
        int bkt = t + 256 * i;
        base[bkt] = bbase[bkt] + ghist[bkt * NBLK + b];
        h[bkt] = 0;
    }
    __syncthreads();
    int e0 = b * epb, e1 = min(e0 + epb, nnz);
    for (int e = e0 + t; e < e1; e += 256) {
        int r = rows[e];
        int bkt = r >> 7;
        int rank = atomicAdd(&h[bkt], 1);
        bedges[base[bkt] + rank] = make_int2(((r & 127) << 20) | cols[e],
                                             __float_as_int(vals[e]));
    }
}

__global__ __launch_bounds__(256) void k_csort(const int* __restrict__ bbase,
                                               const int2* __restrict__ bedges,
                                               int2* __restrict__ edges,
                                               int* __restrict__ rowPtr, int nnz) {
    __shared__ int cntS[128];
    __shared__ int fillS[128];
    __shared__ int wtot;
    int b = blockIdx.x, t = threadIdx.x;
    int s0 = bbase[b];
    int s1 = bbase[b + 1];
    if (t < 128) cntS[t] = 0;
    __syncthreads();
    for (int i = s0 + t; i < s1; i += 256) atomicAdd(&cntS[bedges[i].x >> 20], 1);
    __syncthreads();
    int v = 0, incl = 0;
    if (t < 128) {
        v = cntS[t];
        incl = v;
#pragma unroll
        for (int m = 1; m < 64; m <<= 1) {
            int o = __shfl_up(incl, m, 64);
            if ((t & 63) >= m) incl += o;
        }
        if (t == 63) wtot = incl;
    }
    __syncthreads();
    if (t < 128) {
        int excl = incl - v + ((t >= 64) ? wtot : 0);
        fillS[t] = excl;
        int gr = b * 128 + t;
        if (gr < NN) rowPtr[gr] = s0 + excl;
    }
    if (b == 0 && t == 0) rowPtr[NN] = nnz;
    __syncthreads();
    for (int i = s0 + t; i < s1; i += 256) {
        int2 e = bedges[i];
        int r = e.x >> 20;
        int p = atomicAdd(&fillS[r], 1);
        edges[s0 + p] = make_int2(e.x & 0xFFFFF, e.y);
    }
}

// --------------------------------------------- layer-3 row list (flags) -----
__global__ __launch_bounds__(256) void k_flag(const int* __restrict__ uIdx,
                                              const int* __restrict__ iIdx,
                                              int* __restrict__ flags,
                                              int* __restrict__ cnt, int batch) {
    int i = blockIdx.x * 256 + threadIdx.x;
    if (i == 0) *cnt = 0;
    if (i < batch) flags[uIdx[i]] = 1;
    else if (i < 2 * batch) flags[iIdx[i - batch] + NU] = 1;
}

__global__ __launch_bounds__(256) void k_compact(const int* __restrict__ flags,
                                                 int* __restrict__ list,
                                                 int* __restrict__ cnt) {
    int i = blockIdx.x * 256 + threadIdx.x;
    int f = (i < NN) ? flags[i] : 0;
    unsigned long long mask = __ballot(f);
    int lane = threadIdx.x & 63;
    int total = __popcll(mask);
    int prefix = __popcll(mask & ((1ULL << lane) - 1));
    int base = 0;
    if (lane == 0 && total) base = atomicAdd(cnt, total);
    base = __shfl(base, 0, 64);
    if (f) list[base + prefix] = i;
}

// ---------------------------------------------------------------- wprep -----
__global__ __launch_bounds__(256) void k_wprep(const float* __restrict__ Wlin,
                                               const float* __restrict__ Wint,
                                               uint4* __restrict__ Wb4) {
    int id = blockIdx.x * 256 + threadIdx.x;   // 0..12287
    int lane = id & 63;
    int w = (id >> 6) & 3;
    int s = (id >> 8) & 7;
    int c = (id >> 11) & 1;
    int l = id >> 12;
    const float* src = (c ? Wint : Wlin) + (size_t)l * DD * DD;
    int n = w * 32 + (lane & 31);
    int k0 = s * 16 + ((lane >> 5) & 1) * 8;
    float f[8];
#pragma unroll
    for (int j = 0; j < 8; ++j) f[j] = src[(size_t)(k0 + j) * DD + n];
    Wb4[id] = pk8(f);
}

// ---------------------------------------------------------------- spmm ------
// R6-proven: one wave per row; quarter-wave per edge; 2 edges in flight.
__device__ __forceinline__ void spmm_row(int r, int l,
                                         const int* __restrict__ rowPtr,
                                         const int2* __restrict__ edges,
                                         const ushort_t* __restrict__ fb,
                                         ushort_t* __restrict__ Lxb) {
    int q = l >> 4;
    int d0 = (l & 15) * 8;
    int beg = rowPtr[r], end = rowPtr[r + 1];
    float acc[8] = {0.f, 0.f, 0.f, 0.f, 0.f, 0.f, 0.f, 0.f};
    int e = beg + q;
    for (; e + 4 < end; e += 8) {
        int2 p0 = edges[e];
        int2 p1 = edges[e + 4];
        uint4 g0 = *(const uint4*)(fb + (size_t)p0.x * DD + d0);
        uint4 g1 = *(const uint4*)(fb + (size_t)p1.x * DD + d0);
        float v0 = __int_as_float(p0.y), v1 = __int_as_float(p1.y);
        float x0[8], x1[8];
        unp8(g0, x0);
        unp8(g1, x1);
#pragma unroll
        for (int j = 0; j < 8; ++j) acc[j] = fmaf(v0, x0[j], acc[j]);
#pragma unroll
        for (int j = 0; j < 8; ++j) acc[j] = fmaf(v1, x1[j], acc[j]);
    }
    if (e < end) {
        int2 p0 = edges[e];
        uint4 g0 = *(const uint4*)(fb + (size_t)p0.x * DD + d0);
        float v0 = __int_as_float(p0.y);
        float x0[8];
        unp8(g0, x0);
#pragma unroll
        for (int j = 0; j < 8; ++j) acc[j] = fmaf(v0, x0[j], acc[j]);
    }
#pragma unroll
    for (int j = 0; j < 8; ++j) {
        acc[j] += __shfl_xor(acc[j], 16, 64);
        acc[j] += __shfl_xor(acc[j], 32, 64);
    }
    if (l < 16) *(uint4*)(Lxb + (size_t)r * DD + d0) = pk8(acc);
}

__global__ __launch_bounds__(256) void k_spmm_bf(const int* __restrict__ rowPtr,
                                                 const int2* __restrict__ edges,
                                                 const ushort_t* __restrict__ fb,
                                                 ushort_t* __restrict__ Lxb) {
    int r = blockIdx.x * 4 + (threadIdx.x >> 6);
    if (r >= NN) return;
    spmm_row(r, threadIdx.x & 63, rowPtr, edges, fb, Lxb);
}

__global__ __launch_bounds__(256) void k_spmm_idx(const int* __restrict__ rowPtr,
                                                  const int2* __restrict__ edges,
                                                  const ushort_t* __restrict__ fb,
                                                  ushort_t* __restrict__ Lxb,
                                                  const int* __restrict__ list,
                                                  const int* __restrict__ cnt) {
    int i = blockIdx.x * 4 + (threadIdx.x >> 6);
    if (i >= *cnt) return;
    spmm_row(list[i], threadIdx.x & 63, rowPtr, edges, fb, Lxb);
}

// ---------------------------------------------------------------- layer -----
// BM=64 rows/block: acc[2][16]=32 VGPR -> fits (256,4) without spill; ~19KB LDS.
template <bool INDEXED>
__device__ __forceinline__ void layer_body(const ushort_t* __restrict__ Lxb,
                                           const uint4* __restrict__ Wb4,
                                           const float* __restrict__ blin,
                                           const float* __restrict__ bint,
                                           ushort_t* __restrict__ fb,
                                           const ushort_t* __restrict__ fin,
                                           const int* __restrict__ list, int nc) {
    __shared__ ushort_t As[BM * AROW];     // 17408 B
    __shared__ float pnormAll[BM * 4];     // 1024 B
    __shared__ float rinvS[BM];            // 256 B
    __shared__ int rowIdS[BM];             // 256 B

    const int t = threadIdx.x;
    const int w = t >> 6;
    const int l = t & 63;
    const int q = l >> 5;
    const int ln = l & 31;
    const int n = w * 32 + ln;
    const int m0 = blockIdx.x * BM;

    if (INDEXED && m0 >= nc) return;       // whole block empty (uniform)

    if (t < BM) {
        int gi = m0 + t;
        int gm;
        if (INDEXED) gm = (gi < nc) ? list[gi] : -1;
        else gm = (gi < NN) ? gi : -1;
        rowIdS[t] = gm;
    }
    __syncthreads();

    const float bias = blin[n] + bint[n];

    v16f acc[2];
#pragma unroll
    for (int mt = 0; mt < 2; ++mt)
#pragma unroll
        for (int i = 0; i < 16; ++i) acc[mt][i] = 0.f;

    for (int c = 0; c < 2; ++c) {
        // stage 64 rows x 128 k (chunk c): 1024 16B-pairs over 256 thr
#pragma unroll
        for (int ii = 0; ii < 4; ++ii) {
            int idx = ii * 256 + t;
            int row = idx >> 4;
            int ch = idx & 15;
            int gm = rowIdS[row];
            uint4 outv = make_uint4(0, 0, 0, 0);
            if (gm >= 0) {
                uint4 gl = *(const uint4*)(Lxb + (size_t)gm * DD + ch * 8);
                uint4 gf = *(const uint4*)(fin + (size_t)gm * DD + ch * 8);
                float a[8], b[8], r[8];
                unp8(gl, a);
                unp8(gf, b);
                if (c == 0) {
#pragma unroll
                    for (int j = 0; j < 8; ++j) r[j] = a[j] + b[j];
                } else {
#pragma unroll
                    for (int j = 0; j < 8; ++j) r[j] = a[j] * b[j];
                }
                outv = pk8(r);
            }
            *(uint4*)&As[row * AROW + ch * 8] = outv;
        }
        __syncthreads();

        UB8 bf[8];
#pragma unroll
        for (int s = 0; s < 8; ++s) bf[s].u = Wb4[c * 2048 + s * 256 + w * 64 + l];

#pragma unroll
        for (int mt = 0; mt < 2; ++mt) {
#pragma unroll
            for (int s = 0; s < 8; ++s) {
                v8bf af = *(const v8bf*)&As[(mt * 32 + ln) * AROW + s * 16 + q * 8];
                acc[mt] = __builtin_amdgcn_mfma_f32_32x32x16_bf16(af, bf[s].v, acc[mt], 0, 0, 0);
            }
        }
        __syncthreads();
    }

#pragma unroll
    for (int mt = 0; mt < 2; ++mt) {
        float r[16];
#pragma unroll
        for (int reg = 0; reg < 16; ++reg) {
            float v = acc[mt][reg] + bias;
            v = (v > 0.f) ? v : SLOPE_ * v;
            acc[mt][reg] = v;
            r[reg] = v * v;
        }
#pragma unroll
        for (int lev = 0; lev < 4; ++lev) {
            int m = 1 << lev;
            int cnt2 = 8 >> lev;
            bool hi = (l & m) != 0;
#pragma unroll
            for (int i = 0; i < 8; ++i) {
                if (i < cnt2) {
                    float p = hi ? r[2 * i + 1] : r[2 * i];
                    float qv = hi ? r[2 * i] : r[2 * i + 1];
                    r[i] = p + __shfl_xor(qv, m, 64);
                }
            }
        }
        float tot = r[0] + __shfl_xor(r[0], 16, 64);
        if ((l & 31) < 16) {
            int i = l & 15;
            int row = (i & 3) + ((i >> 2) << 3) + 4 * q;
            pnormAll[(mt * 32 + row) * 4 + w] = tot;
        }
    }
    __syncthreads();
    if (t < BM) {
        float4 p = *(const float4*)&pnormAll[t * 4];
        float tot = p.x + p.y + p.z + p.w;
        rinvS[t] = 1.0f / fmaxf(sqrtf(tot), EPS_);
    }
    __syncthreads();

#pragma unroll
    for (int mt = 0; mt < 2; ++mt) {
#pragma unroll
        for (int reg = 0; reg < 16; ++reg) {
            int row = (reg & 3) + ((reg >> 2) << 3) + 4 * q;
            int gm = rowIdS[mt * 32 + row];
            if (gm >= 0)
                fb[(size_t)gm * DD + n] = f2bf1(acc[mt][reg] * rinvS[mt * 32 + row]);
        }
    }
}

__global__ __launch_bounds__(256, 4) void k_layer2(const ushort_t* __restrict__ Lxb,
                                                   const uint4* __restrict__ Wb4,
                                                   const float* __restrict__ blin,
                                                   const float* __restrict__ bint,
                                                   const ushort_t* __restrict__ fin,
                                                   ushort_t* __restrict__ fb) {
    layer_body<false>(Lxb, Wb4, blin, bint, fb, fin, nullptr, 0);
}

__global__ __launch_bounds__(256, 4) void k_layer_idx(const ushort_t* __restrict__ Lxb,
                                                      const uint4* __restrict__ Wb4,
                                                      const float* __restrict__ blin,
                                                      const float* __restrict__ bint,
                                                      const ushort_t* __restrict__ fin,
                                                      ushort_t* __restrict__ fb,
                                                      const int* __restrict__ list,
                                                      const int* __restrict__ cnt) {
    layer_body<true>(Lxb, Wb4, blin, bint, fb, fin, list, *cnt);
}

// ---------------------------------------------------------------- launch ----
extern "C" void kernel_launch(void* const* d_in, const int* in_sizes, int n_in,
                              void* d_out, int out_size, void* d_ws, size_t ws_size,
                              hipStream_t stream) {
    const int*   userIdx = (const int*)d_in[0];
    const int*   itemIdx = (const int*)d_in[1];
    const int*   rows    = (const int*)d_in[2];
    const int*   cols    = (const int*)d_in[3];
    const float* vals    = (const float*)d_in[4];
    const float* uE      = (const float*)d_in[5];
    const float* iE      = (const float*)d_in[6];
    const float* Wlin    = (const float*)d_in[7];
    const float* blin    = (const float*)d_in[8];
    const float* Wint    = (const float*)d_in[9];
    const float* bint    = (const float*)d_in[10];
    float* out = (float*)d_out;

    const int batch = in_sizes[0];
    const int nnz   = in_sizes[2];
    const int epb   = (nnz + NBLK - 1) / NBLK;

    // ---- workspace layout ----
    ushort_t* featA = (ushort_t*)d_ws;                       // 25.6 MB
    ushort_t* featB = featA + (size_t)NN * DD;               // 25.6 MB (ping-pong)
    ushort_t* Lxb   = featB + (size_t)NN * DD;               // 25.6 MB
    uint4* Wb4      = (uint4*)(Lxb + (size_t)NN * DD);       // 196 KB
    int2*  bedges   = (int2*)(Wb4 + 12288);                  // 8 MB
    int2*  edges    = bedges + nnz;                          // 8 MB
    int*   ghist    = (int*)(edges + nnz);                   // 1 MB
    int*   btot     = ghist + NBKT * NBLK;                   // 4 KB
    int*   bbase    = btot + NBKT;                           // 4 KB (+1)
    int*   rowPtr   = bbase + NBKT + 4;                      // NN+1
    int*   flags    = rowPtr + NN + 4;                       // 400 KB
    int*   list     = flags + NN;                            // 128 KB
    int*   cnt      = list + MAXL;                           // 4 B

    k_concat_bf<<<(NN * DD / 8 + 255) / 256, 256, 0, stream>>>(uE, iE, featA);
    k_wprep<<<48, 256, 0, stream>>>(Wlin, Wint, Wb4);

    // ---- contention-free CSR build (hierarchical scan) ----
    k_lhist<<<NBLK, 256, 0, stream>>>(rows, ghist, nnz, epb);
    k_rscan<<<NBKT / 4, 256, 0, stream>>>(ghist, btot);
    k_btscan<<<1, 256, 0, stream>>>(btot, bbase);
    k_sscatter<<<NBLK, 256, 0, stream>>>(rows, cols, vals, ghist, bbase, bedges, nnz, epb);
    k_csort<<<NB, 256, 0, stream>>>(bbase, bedges, edges, rowPtr, nnz);

    // ---- layer-3 row list ----
    k_zero<<<(NN / 4 + 255) / 256, 256, 0, stream>>>((float4*)flags, NN / 4);
    k_flag<<<(2 * batch + 255) / 256, 256, 0, stream>>>(userIdx, itemIdx, flags, cnt, batch);
    k_compact<<<(NN + 255) / 256, 256, 0, stream>>>(flags, list, cnt);

    k_dot<<<(batch + 3) / 4, 256, 0, stream>>>(featA, userIdx, itemIdx, out, batch, 0);

    // layer 1: featA -> featB
    k_spmm_bf<<<(NN + 3) / 4, 256, 0, stream>>>(rowPtr, edges, featA, Lxb);
    k_layer2<<<(NN + BM - 1) / BM, 256, 0, stream>>>(
        Lxb, Wb4, blin, bint, featA, featB);
    k_dot<<<(batch + 3) / 4, 256, 0, stream>>>(featB, userIdx, itemIdx, out, batch, 1);

    // layer 2: featB -> featA
    k_spmm_bf<<<(NN + 3) / 4, 256, 0, stream>>>(rowPtr, edges, featB, Lxb);
    k_layer2<<<(NN + BM - 1) / BM, 256, 0, stream>>>(
        Lxb, Wb4 + 4096, blin + DD, bint + DD, featB, featA);
    k_dot<<<(batch + 3) / 4, 256, 0, stream>>>(featA, userIdx, itemIdx, out, batch, 1);

    // layer 3 (sparse rows): featA -> featB, only listed rows
    k_spmm_idx<<<(MAXL + 3) / 4, 256, 0, stream>>>(rowPtr, edges, featA, Lxb, list, cnt);
    k_layer_idx<<<(MAXL + BM - 1) / BM, 256, 0, stream>>>(
        Lxb, Wb4 + 8192, blin + 2 * DD, bint + 2 * DD, featA, featB, list, cnt);
    k_dot<<<(batch + 3) / 4, 256, 0, stream>>>(featB, userIdx, itemIdx, out, batch, 1);
}

// Round 11
// 366.606 us; speedup vs baseline: 1.1524x; 1.0334x over previous
//
#include <hip/hip_runtime.h>
#include <hip/hip_bf16.h>

#define NU 30000
#define NI 70000
#define NN 100000
#define DD 128
#define NLAYERS 3
#define SLOPE_ 0.01f
#define EPS_ 1e-12f

#define NB 782                 // row buckets of 128 rows
#define NBKT 1024              // padded bucket count (pow2)
#define NBLK 256               // scatter blocks
#define AROW 136               // LDS A row stride in ushorts (272B = 17*16B)
#define MAXL 32768             // max compacted rows for layer 3
#define BM 64                  // layer kernel M-tile (64 rows/block)

typedef __bf16 v8bf __attribute__((ext_vector_type(8)));
typedef float v16f __attribute__((ext_vector_type(16)));
typedef float v2f __attribute__((ext_vector_type(2)));
typedef unsigned short ushort_t;

union UB8 { uint4 u; v8bf v; };

__device__ __forceinline__ float bflo(unsigned u) { return __uint_as_float(u << 16); }
__device__ __forceinline__ float bfhi(unsigned u) { return __uint_as_float(u & 0xffff0000u); }

__device__ __forceinline__ unsigned pk2(float a, float b) {
    __hip_bfloat162 h = __float22bfloat162_rn(make_float2(a, b));
    return *reinterpret_cast<unsigned*>(&h);
}
__device__ __forceinline__ uint4 pk8(const float* f) {
    return make_uint4(pk2(f[0], f[1]), pk2(f[2], f[3]), pk2(f[4], f[5]), pk2(f[6], f[7]));
}
__device__ __forceinline__ void unp8(uint4 g, float* f) {
    f[0] = bflo(g.x); f[1] = bfhi(g.x);
    f[2] = bflo(g.y); f[3] = bfhi(g.y);
    f[4] = bflo(g.z); f[5] = bfhi(g.z);
    f[6] = bflo(g.w); f[7] = bfhi(g.w);
}
__device__ __forceinline__ ushort_t f2bf1(float x) {
    __hip_bfloat16 h = __float2bfloat16(x);
    return *reinterpret_cast<ushort_t*>(&h);
}

// ---------------------------------------------------------------- concat ----
__global__ __launch_bounds__(256) void k_concat_bf(const float* __restrict__ u,
                                                   const float* __restrict__ it,
                                                   ushort_t* __restrict__ fb) {
    int idx = blockIdx.x * 256 + threadIdx.x;
    if (idx >= NN * DD / 8) return;
    size_t base = (size_t)idx * 8;
    const float* src = (base < (size_t)NU * DD) ? (u + base) : (it + base - (size_t)NU * DD);
    float f[8];
    float4 a = *(const float4*)src;
    float4 b = *(const float4*)(src + 4);
    f[0] = a.x; f[1] = a.y; f[2] = a.z; f[3] = a.w;
    f[4] = b.x; f[5] = b.y; f[6] = b.z; f[7] = b.w;
    *(uint4*)(fb + base) = pk8(f);
}

// ---------------------------------------------------------------- dot -------
__device__ __forceinline__ void dot_body(const ushort_t* __restrict__ fb,
                                         const int* __restrict__ uIdx,
                                         const int* __restrict__ iIdx,
                                         float* __restrict__ out,
                                         int batch, int accum, int blk, int t) {
    int b = blk * 4 + (t >> 6);
    if (b >= batch) return;
    int lane = t & 63;
    unsigned ua = *(const unsigned*)(fb + (size_t)uIdx[b] * DD + lane * 2);
    unsigned ib = *(const unsigned*)(fb + (size_t)(iIdx[b] + NU) * DD + lane * 2);
    float s = bflo(ua) * bflo(ib) + bfhi(ua) * bfhi(ib);
#pragma unroll
    for (int m = 32; m; m >>= 1) s += __shfl_xor(s, m, 64);
    if (lane == 0) out[b] = accum ? out[b] + s : s;
}

__global__ __launch_bounds__(256) void k_dot(const ushort_t* __restrict__ fb,
                                             const int* __restrict__ uIdx,
                                             const int* __restrict__ iIdx,
                                             float* __restrict__ out,
                                             int batch, int accum) {
    dot_body(fb, uIdx, iIdx, out, batch, accum, blockIdx.x, threadIdx.x);
}

// ------------------------------------------------- contention-free CSR build
// pass 1: per-block LDS histograms; also zeroes layer-3 flags array.
__global__ __launch_bounds__(256) void k_lhist(const int* __restrict__ rows,
                                               int* __restrict__ ghist,
                                               int* __restrict__ flags,
                                               int nnz, int epb) {
    __shared__ int h[NBKT];
    int t = threadIdx.x, b = blockIdx.x;
#pragma unroll
    for (int i = 0; i < 4; ++i) h[t + 256 * i] = 0;
    // zero flags (independent, no barrier needed before use in later kernels)
    for (int i = b * 256 + t; i < NN; i += NBLK * 256) flags[i] = 0;
    __syncthreads();
    int e0 = b * epb, e1 = min(e0 + epb, nnz);
    for (int e = e0 + t; e < e1; e += 256) atomicAdd(&h[rows[e] >> 7], 1);
    __syncthreads();
#pragma unroll
    for (int i = 0; i < 4; ++i) {
        int bkt = t + 256 * i;
        ghist[bkt * NBLK + b] = h[bkt];
    }
}

// pass 2a: per-bucket scan of block counts; also sets layer-3 flags + cnt=0.
__global__ __launch_bounds__(256) void k_rscan(int* __restrict__ ghist,
                                               int* __restrict__ btot,
                                               const int* __restrict__ uIdx,
                                               const int* __restrict__ iIdx,
                                               int* __restrict__ flags,
                                               int* __restrict__ cnt, int batch) {
    int t = threadIdx.x;
    int gid = blockIdx.x * 256 + t;          // 0..65535 covers 2*batch=32768
    if (gid == 0) *cnt = 0;
    if (gid < batch) flags[uIdx[gid]] = 1;
    else if (gid < 2 * batch) flags[iIdx[gid - batch] + NU] = 1;

    int bkt = blockIdx.x * 4 + (t >> 6);
    int lane = t & 63;
    int* row = ghist + bkt * NBLK;
    int4 c = *(const int4*)(row + lane * 4);
    int s = c.x + c.y + c.z + c.w;
    int incl = s;
#pragma unroll
    for (int m = 1; m < 64; m <<= 1) {
        int o = __shfl_up(incl, m, 64);
        if (lane >= m) incl += o;
    }
    int excl = incl - s;
    int4 o;
    o.x = excl;
    o.y = o.x + c.x;
    o.z = o.y + c.y;
    o.w = o.z + c.z;
    *(int4*)(row + lane * 4) = o;
    if (lane == 63) btot[bkt] = incl;
}

__global__ __launch_bounds__(256) void k_btscan(const int* __restrict__ btot,
                                                int* __restrict__ bbase) {
    int t = threadIdx.x;
    int4 c = *(const int4*)(btot + t * 4);
    int tsum = c.x + c.y + c.z + c.w;
    int incl = tsum;
#pragma unroll
    for (int m = 1; m < 64; m <<= 1) {
        int o = __shfl_up(incl, m, 64);
        if ((t & 63) >= m) incl += o;
    }
    __shared__ int wsum[4];
    if ((t & 63) == 63) wsum[t >> 6] = incl;
    __syncthreads();
    int off = 0;
    for (int i = 0; i < (t >> 6); ++i) off += wsum[i];
    int excl = off + incl - tsum;
    int4 o;
    o.x = excl;
    o.y = o.x + c.x;
    o.z = o.y + c.y;
    o.w = o.z + c.z;
    *(int4*)(bbase + t * 4) = o;
    if (t == 255) bbase[NBKT] = o.w + c.w;
}

// pass 3: scatter to bucket order; also wave-aggregated compaction of flags.
__global__ __launch_bounds__(256) void k_sscatter(const int* __restrict__ rows,
                                                  const int* __restrict__ cols,
                                                  const float* __restrict__ vals,
                                                  const int* __restrict__ ghist,
                                                  const int* __restrict__ bbase,
                                                  int2* __restrict__ bedges,
                                                  const int* __restrict__ flags,
                                                  int* __restrict__ list,
                                                  int* __restrict__ cnt,
                                                  int nnz, int epb) {
    __shared__ int base[NBKT];
    __shared__ int h[NBKT];
    int t = threadIdx.x, b = blockIdx.x;
#pragma unroll
    for (int i = 0; i < 4; ++i) {
        int bkt = t + 256 * i;
        base[bkt] = bbase[bkt] + ghist[bkt * NBLK + b];
        h[bkt] = 0;
    }
    // compaction (flags final after k_rscan; cnt zeroed there)
    int lane = t & 63;
    for (int i = b * 256 + t; i < ((NN + 65535) & ~65535); i += NBLK * 256) {
        int f = (i < NN) ? flags[i] : 0;
        unsigned long long mask = __ballot(f);
        int total = __popcll(mask);
        int prefix = __popcll(mask & ((1ULL << lane) - 1));
        int bs = 0;
        if (lane == 0 && total) bs = atomicAdd(cnt, total);
        bs = __shfl(bs, 0, 64);
        if (f) list[bs + prefix] = i;
    }
    __syncthreads();
    int e0 = b * epb, e1 = min(e0 + epb, nnz);
    for (int e = e0 + t; e < e1; e += 256) {
        int r = rows[e];
        int bkt = r >> 7;
        int rank = atomicAdd(&h[bkt], 1);
        bedges[base[bkt] + rank] = make_int2(((r & 127) << 20) | cols[e],
                                             __float_as_int(vals[e]));
    }
}

__global__ __launch_bounds__(256) void k_csort(const int* __restrict__ bbase,
                                               const int2* __restrict__ bedges,
                                               int2* __restrict__ edges,
                                               int* __restrict__ rowPtr, int nnz) {
    __shared__ int cntS[128];
    __shared__ int fillS[128];
    __shared__ int wtot;
    int b = blockIdx.x, t = threadIdx.x;
    int s0 = bbase[b];
    int s1 = bbase[b + 1];
    if (t < 128) cntS[t] = 0;
    __syncthreads();
    for (int i = s0 + t; i < s1; i += 256) atomicAdd(&cntS[bedges[i].x >> 20], 1);
    __syncthreads();
    int v = 0, incl = 0;
    if (t < 128) {
        v = cntS[t];
        incl = v;
#pragma unroll
        for (int m = 1; m < 64; m <<= 1) {
            int o = __shfl_up(incl, m, 64);
            if ((t & 63) >= m) incl += o;
        }
        if (t == 63) wtot = incl;
    }
    __syncthreads();
    if (t < 128) {
        int excl = incl - v + ((t >= 64) ? wtot : 0);
        fillS[t] = excl;
        int gr = b * 128 + t;
        if (gr < NN) rowPtr[gr] = s0 + excl;
    }
    if (b == 0 && t == 0) rowPtr[NN] = nnz;
    __syncthreads();
    for (int i = s0 + t; i < s1; i += 256) {
        int2 e = bedges[i];
        int r = e.x >> 20;
        int p = atomicAdd(&fillS[r], 1);
        edges[s0 + p] = make_int2(e.x & 0xFFFFF, e.y);
    }
}

// ---------------------------------------------------------------- wprep -----
__global__ __launch_bounds__(256) void k_wprep(const float* __restrict__ Wlin,
                                               const float* __restrict__ Wint,
                                               uint4* __restrict__ Wb4) {
    int id = blockIdx.x * 256 + threadIdx.x;   // 0..12287
    int lane = id & 63;
    int w = (id >> 6) & 3;
    int s = (id >> 8) & 7;
    int c = (id >> 11) & 1;
    int l = id >> 12;
    const float* src = (c ? Wint : Wlin) + (size_t)l * DD * DD;
    int n = w * 32 + (lane & 31);
    int k0 = s * 16 + ((lane >> 5) & 1) * 8;
    float f[8];
#pragma unroll
    for (int j = 0; j < 8; ++j) f[j] = src[(size_t)(k0 + j) * DD + n];
    Wb4[id] = pk8(f);
}

// ---------------------------------------------------------------- spmm ------
// one wave per row; quarter-wave per edge; 2 edges in flight; float2 packed
// math in the accumulate (v_pk_fma_f32 path).
__device__ __forceinline__ void acc_pk(v2f* acc2, uint4 g, float v) {
    v2f vv = {v, v};
    unsigned gw[4] = {g.x, g.y, g.z, g.w};
#pragma unroll
    for (int p = 0; p < 4; ++p) {
        v2f x = {bflo(gw[p]), bfhi(gw[p])};
        acc2[p] = x * vv + acc2[p];
    }
}

__device__ __forceinline__ void spmm_row(int r, int l,
                                         const int* __restrict__ rowPtr,
                                         const int2* __restrict__ edges,
                                         const ushort_t* __restrict__ fb,
                                         ushort_t* __restrict__ Lxb) {
    int q = l >> 4;
    int d0 = (l & 15) * 8;
    int beg = rowPtr[r], end = rowPtr[r + 1];
    v2f acc2[4];
#pragma unroll
    for (int p = 0; p < 4; ++p) acc2[p] = (v2f){0.f, 0.f};
    int e = beg + q;
    for (; e + 4 < end; e += 8) {
        int2 p0 = edges[e];
        int2 p1 = edges[e + 4];
        uint4 g0 = *(const uint4*)(fb + (size_t)p0.x * DD + d0);
        uint4 g1 = *(const uint4*)(fb + (size_t)p1.x * DD + d0);
        acc_pk(acc2, g0, __int_as_float(p0.y));
        acc_pk(acc2, g1, __int_as_float(p1.y));
    }
    if (e < end) {
        int2 p0 = edges[e];
        uint4 g0 = *(const uint4*)(fb + (size_t)p0.x * DD + d0);
        acc_pk(acc2, g0, __int_as_float(p0.y));
    }
    float acc[8];
#pragma unroll
    for (int p = 0; p < 4; ++p) { acc[2 * p] = acc2[p][0]; acc[2 * p + 1] = acc2[p][1]; }
#pragma unroll
    for (int j = 0; j < 8; ++j) {
        acc[j] += __shfl_xor(acc[j], 16, 64);
        acc[j] += __shfl_xor(acc[j], 32, 64);
    }
    if (l < 16) *(uint4*)(Lxb + (size_t)r * DD + d0) = pk8(acc);
}

// spmm with dot-product blocks prefixed (dot reads same feature buffer)
__global__ __launch_bounds__(256) void k_spmm_dot(const int* __restrict__ rowPtr,
                                                  const int2* __restrict__ edges,
                                                  const ushort_t* __restrict__ fb,
                                                  ushort_t* __restrict__ Lxb,
                                                  const int* __restrict__ uIdx,
                                                  const int* __restrict__ iIdx,
                                                  float* __restrict__ out,
                                                  int batch, int accum, int dotBlocks) {
    if ((int)blockIdx.x < dotBlocks) {
        dot_body(fb, uIdx, iIdx, out, batch, accum, blockIdx.x, threadIdx.x);
        return;
    }
    int r = (blockIdx.x - dotBlocks) * 4 + (threadIdx.x >> 6);
    if (r >= NN) return;
    spmm_row(r, threadIdx.x & 63, rowPtr, edges, fb, Lxb);
}

__global__ __launch_bounds__(256) void k_spmm_idx_dot(const int* __restrict__ rowPtr,
                                                      const int2* __restrict__ edges,
                                                      const ushort_t* __restrict__ fb,
                                                      ushort_t* __restrict__ Lxb,
                                                      const int* __restrict__ list,
                                                      const int* __restrict__ cnt,
                                                      const int* __restrict__ uIdx,
                                                      const int* __restrict__ iIdx,
                                                      float* __restrict__ out,
                                                      int batch, int dotBlocks) {
    if ((int)blockIdx.x < dotBlocks) {
        dot_body(fb, uIdx, iIdx, out, batch, 1, blockIdx.x, threadIdx.x);
        return;
    }
    int i = (blockIdx.x - dotBlocks) * 4 + (threadIdx.x >> 6);
    if (i >= *cnt) return;
    spmm_row(list[i], threadIdx.x & 63, rowPtr, edges, fb, Lxb);
}

// ---------------------------------------------------------------- layer -----
// BM=64 rows/block: acc[2][16]=32 VGPR -> fits (256,4) without spill; ~19KB LDS.
template <bool INDEXED>
__device__ __forceinline__ void layer_body(const ushort_t* __restrict__ Lxb,
                                           const uint4* __restrict__ Wb4,
                                           const float* __restrict__ blin,
                                           const float* __restrict__ bint,
                                           ushort_t* __restrict__ fb,
                                           const ushort_t* __restrict__ fin,
                                           const int* __restrict__ list, int nc) {
    __shared__ ushort_t As[BM * AROW];     // 17408 B
    __shared__ float pnormAll[BM * 4];     // 1024 B
    __shared__ float rinvS[BM];            // 256 B
    __shared__ int rowIdS[BM];             // 256 B

    const int t = threadIdx.x;
    const int w = t >> 6;
    const int l = t & 63;
    const int q = l >> 5;
    const int ln = l & 31;
    const int n = w * 32 + ln;
    const int m0 = blockIdx.x * BM;

    if (INDEXED && m0 >= nc) return;       // whole block empty (uniform)

    if (t < BM) {
        int gi = m0 + t;
        int gm;
        if (INDEXED) gm = (gi < nc) ? list[gi] : -1;
        else gm = (gi < NN) ? gi : -1;
        rowIdS[t] = gm;
    }
    __syncthreads();

    const float bias = blin[n] + bint[n];

    v16f acc[2];
#pragma unroll
    for (int mt = 0; mt < 2; ++mt)
#pragma unroll
        for (int i = 0; i < 16; ++i) acc[mt][i] = 0.f;

    for (int c = 0; c < 2; ++c) {
#pragma unroll
        for (int ii = 0; ii < 4; ++ii) {
            int idx = ii * 256 + t;
            int row = idx >> 4;
            int ch = idx & 15;
            int gm = rowIdS[row];
            uint4 outv = make_uint4(0, 0, 0, 0);
            if (gm >= 0) {
                uint4 gl = *(const uint4*)(Lxb + (size_t)gm * DD + ch * 8);
                uint4 gf = *(const uint4*)(fin + (size_t)gm * DD + ch * 8);
                float a[8], b[8], r[8];
                unp8(gl, a);
                unp8(gf, b);
                if (c == 0) {
#pragma unroll
                    for (int j = 0; j < 8; ++j) r[j] = a[j] + b[j];
                } else {
#pragma unroll
                    for (int j = 0; j < 8; ++j) r[j] = a[j] * b[j];
                }
                outv = pk8(r);
            }
            *(uint4*)&As[row * AROW + ch * 8] = outv;
        }
        __syncthreads();

        UB8 bf[8];
#pragma unroll
        for (int s = 0; s < 8; ++s) bf[s].u = Wb4[c * 2048 + s * 256 + w * 64 + l];

#pragma unroll
        for (int mt = 0; mt < 2; ++mt) {
#pragma unroll
            for (int s = 0; s < 8; ++s) {
                v8bf af = *(const v8bf*)&As[(mt * 32 + ln) * AROW + s * 16 + q * 8];
                acc[mt] = __builtin_amdgcn_mfma_f32_32x32x16_bf16(af, bf[s].v, acc[mt], 0, 0, 0);
            }
        }
        __syncthreads();
    }

#pragma unroll
    for (int mt = 0; mt < 2; ++mt) {
        float r[16];
#pragma unroll
        for (int reg = 0; reg < 16; ++reg) {
            float v = acc[mt][reg] + bias;
            v = (v > 0.f) ? v : SLOPE_ * v;
            acc[mt][reg] = v;
            r[reg] = v * v;
        }
#pragma unroll
        for (int lev = 0; lev < 4; ++lev) {
            int m = 1 << lev;
            int cnt2 = 8 >> lev;
            bool hi = (l & m) != 0;
#pragma unroll
            for (int i = 0; i < 8; ++i) {
                if (i < cnt2) {
                    float p = hi ? r[2 * i + 1] : r[2 * i];
                    float qv = hi ? r[2 * i] : r[2 * i + 1];
                    r[i] = p + __shfl_xor(qv, m, 64);
                }
            }
        }
        float tot = r[0] + __shfl_xor(r[0], 16, 64);
        if ((l & 31) < 16) {
            int i = l & 15;
            int row = (i & 3) + ((i >> 2) << 3) + 4 * q;
            pnormAll[(mt * 32 + row) * 4 + w] = tot;
        }
    }
    __syncthreads();
    if (t < BM) {
        float4 p = *(const float4*)&pnormAll[t * 4];
        float tot = p.x + p.y + p.z + p.w;
        rinvS[t] = 1.0f / fmaxf(sqrtf(tot), EPS_);
    }
    __syncthreads();

#pragma unroll
    for (int mt = 0; mt < 2; ++mt) {
#pragma unroll
        for (int reg = 0; reg < 16; ++reg) {
            int row = (reg & 3) + ((reg >> 2) << 3) + 4 * q;
            int gm = rowIdS[mt * 32 + row];
            if (gm >= 0)
                fb[(size_t)gm * DD + n] = f2bf1(acc[mt][reg] * rinvS[mt * 32 + row]);
        }
    }
}

__global__ __launch_bounds__(256, 4) void k_layer2(const ushort_t* __restrict__ Lxb,
                                                   const uint4* __restrict__ Wb4,
                                                   const float* __restrict__ blin,
                                                   const float* __restrict__ bint,
                                                   const ushort_t* __restrict__ fin,
                                                   ushort_t* __restrict__ fb) {
    layer_body<false>(Lxb, Wb4, blin, bint, fb, fin, nullptr, 0);
}

__global__ __launch_bounds__(256, 4) void k_layer_idx(const ushort_t* __restrict__ Lxb,
                                                      const uint4* __restrict__ Wb4,
                                                      const float* __restrict__ blin,
                                                      const float* __restrict__ bint,
                                                      const ushort_t* __restrict__ fin,
                                                      ushort_t* __restrict__ fb,
                                                      const int* __restrict__ list,
                                                      const int* __restrict__ cnt) {
    layer_body<true>(Lxb, Wb4, blin, bint, fb, fin, list, *cnt);
}

// ---------------------------------------------------------------- launch ----
extern "C" void kernel_launch(void* const* d_in, const int* in_sizes, int n_in,
                              void* d_out, int out_size, void* d_ws, size_t ws_size,
                              hipStream_t stream) {
    const int*   userIdx = (const int*)d_in[0];
    const int*   itemIdx = (const int*)d_in[1];
    const int*   rows    = (const int*)d_in[2];
    const int*   cols    = (const int*)d_in[3];
    const float* vals    = (const float*)d_in[4];
    const float* uE      = (const float*)d_in[5];
    const float* iE      = (const float*)d_in[6];
    const float* Wlin    = (const float*)d_in[7];
    const float* blin    = (const float*)d_in[8];
    const float* Wint    = (const float*)d_in[9];
    const float* bint    = (const float*)d_in[10];
    float* out = (float*)d_out;

    const int batch = in_sizes[0];
    const int nnz   = in_sizes[2];
    const int epb   = (nnz + NBLK - 1) / NBLK;
    const int dotBlocks = (batch + 3) / 4;

    // ---- workspace layout ----
    ushort_t* featA = (ushort_t*)d_ws;                       // 25.6 MB
    ushort_t* featB = featA + (size_t)NN * DD;               // 25.6 MB (ping-pong)
    ushort_t* Lxb   = featB + (size_t)NN * DD;               // 25.6 MB
    uint4* Wb4      = (uint4*)(Lxb + (size_t)NN * DD);       // 196 KB
    int2*  bedges   = (int2*)(Wb4 + 12288);                  // 8 MB
    int2*  edges    = bedges + nnz;                          // 8 MB
    int*   ghist    = (int*)(edges + nnz);                   // 1 MB
    int*   btot     = ghist + NBKT * NBLK;                   // 4 KB
    int*   bbase    = btot + NBKT;                           // 4 KB (+1)
    int*   rowPtr   = bbase + NBKT + 4;                      // NN+1
    int*   flags    = rowPtr + NN + 4;                       // 400 KB
    int*   list     = flags + NN;                            // 128 KB
    int*   cnt      = list + MAXL;                           // 4 B

    k_concat_bf<<<(NN * DD / 8 + 255) / 256, 256, 0, stream>>>(uE, iE, featA);
    k_wprep<<<48, 256, 0, stream>>>(Wlin, Wint, Wb4);

    // ---- contention-free CSR build (hierarchical scan) + layer-3 row list --
    k_lhist<<<NBLK, 256, 0, stream>>>(rows, ghist, flags, nnz, epb);
    k_rscan<<<NBKT / 4, 256, 0, stream>>>(ghist, btot, userIdx, itemIdx, flags, cnt, batch);
    k_btscan<<<1, 256, 0, stream>>>(btot, bbase);
    k_sscatter<<<NBLK, 256, 0, stream>>>(rows, cols, vals, ghist, bbase, bedges,
                                         flags, list, cnt, nnz, epb);
    k_csort<<<NB, 256, 0, stream>>>(bbase, bedges, edges, rowPtr, nnz);

    // layer 1: featA -> featB   (dot-0 on featA fused into spmm grid)
    k_spmm_dot<<<dotBlocks + (NN + 3) / 4, 256, 0, stream>>>(
        rowPtr, edges, featA, Lxb, userIdx, itemIdx, out, batch, 0, dotBlocks);
    k_layer2<<<(NN + BM - 1) / BM, 256, 0, stream>>>(
        Lxb, Wb4, blin, bint, featA, featB);

    // layer 2: featB -> featA   (dot-1 on featB fused)
    k_spmm_dot<<<dotBlocks + (NN + 3) / 4, 256, 0, stream>>>(
        rowPtr, edges, featB, Lxb, userIdx, itemIdx, out, batch, 1, dotBlocks);
    k_layer2<<<(NN + BM - 1) / BM, 256, 0, stream>>>(
        Lxb, Wb4 + 4096, blin + DD, bint + DD, featB, featA);

    // layer 3 (sparse rows): featA -> featB   (dot-2 on featA fused)
    k_spmm_idx_dot<<<dotBlocks + (MAXL + 3) / 4, 256, 0, stream>>>(
        rowPtr, edges, featA, Lxb, list, cnt, userIdx, itemIdx, out, batch, dotBlocks);
    k_layer_idx<<<(MAXL + BM - 1) / BM, 256, 0, stream>>>(
        Lxb, Wb4 + 8192, blin + 2 * DD, bint + 2 * DD, featA, featB, list, cnt);

    // final dot on featB
    k_dot<<<dotBlocks, 256, 0, stream>>>(featB, userIdx, itemIdx, out, batch, 1);
}